// Round 1
// baseline (1437.107 us; speedup 1.0000x reference)
//
#include <hip/hip_runtime.h>
#include <hip/hip_bf16.h>

#define VOCAB 50000
#define EMBD  512
#define HID   1024
#define NBATCH 256
#define SEQW  26
#define KTOT  (EMBD + HID)   /* 1536 */

typedef short short8 __attribute__((ext_vector_type(8)));
typedef float f32x4  __attribute__((ext_vector_type(4)));

__device__ __forceinline__ unsigned short f2bf_bits(float x) {
    union { __hip_bfloat16 b; unsigned short u; } cv;
    cv.b = __float2bfloat16(x);
    return cv.u;
}

__device__ __forceinline__ void split_bf16(float x, unsigned short& hi, unsigned short& lo) {
    __hip_bfloat16 h = __float2bfloat16(x);
    float hf = __bfloat162float(h);
    hi = f2bf_bits(x);            // same as bits of h
    lo = f2bf_bits(x - hf);
}

// ---------------- init: zero c and h0 (hi/lo) ----------------
__global__ void init_kernel(float* __restrict__ c,
                            unsigned short* __restrict__ hHi0,
                            unsigned short* __restrict__ hLo0) {
    int idx = (blockIdx.x * blockDim.x + threadIdx.x) * 4;
    #pragma unroll
    for (int k = 0; k < 4; ++k) {
        c[idx + k] = 0.0f;
        hHi0[idx + k] = 0;
        hLo0[idx + k] = 0;
    }
}

// ---------------- embedding: gather + tanh -> bf16 hi/lo ----------------
// grid: SEQW*NBATCH blocks of 64 threads; block = t*NBATCH + b
__global__ void embed_kernel(const int* __restrict__ qv,
                             const float* __restrict__ Wemb,
                             unsigned short* __restrict__ eHi,
                             unsigned short* __restrict__ eLo) {
    int t = blockIdx.x / NBATCH;
    int b = blockIdx.x % NBATCH;
    int tok = qv[b * SEQW + t];
    int lane = threadIdx.x;
    size_t base = (size_t)(t * NBATCH + b) * EMBD;
    if (tok > 0) {
        int v = tok - 1;
        for (int e = lane; e < EMBD; e += 64) {
            float x = Wemb[(size_t)e * VOCAB + v];
            float y = tanhf(x);
            unsigned short hi, lo;
            split_bf16(y, hi, lo);
            eHi[base + e] = hi;
            eLo[base + e] = lo;
        }
    } else {
        for (int e = lane; e < EMBD; e += 64) {
            eHi[base + e] = 0;
            eLo[base + e] = 0;
        }
    }
}

// ---------------- weight concat + bf16 split: Wcat[4096][1536] ----------------
__global__ void convw_kernel(const float* __restrict__ Wih,
                             const float* __restrict__ Whh,
                             unsigned short* __restrict__ wHi,
                             unsigned short* __restrict__ wLo) {
    int j = blockIdx.x; // 0..4095
    for (int col = threadIdx.x; col < KTOT; col += blockDim.x) {
        float x = (col < EMBD) ? Wih[(size_t)j * EMBD + col]
                               : Whh[(size_t)j * HID + (col - EMBD)];
        unsigned short hi, lo;
        split_bf16(x, hi, lo);
        wHi[(size_t)j * KTOT + col] = hi;
        wLo[(size_t)j * KTOT + col] = lo;
    }
}

// ---------------- one LSTM step ----------------
// grid (8, 32): blockIdx.x = batch tile (32 rows), blockIdx.y = jh tile (32 cols in [0,1024))
// 256 threads = 4 waves; wave g computes gate g's 32x32 tile (2x2 16x16 MFMA fragments).
__device__ __forceinline__ void do_k32(
    const unsigned short* __restrict__ aHiBase, const unsigned short* __restrict__ aLoBase,
    int lda, int kloc,
    const unsigned short* __restrict__ WHi, const unsigned short* __restrict__ WLo,
    int kglob, int m0, int jabs0, int col16, int g4, f32x4 (&acc)[2][2])
{
    short8 aHi[2], aLo[2], bHi[2], bLo[2];
    int ka = kloc + 8 * g4;
    #pragma unroll
    for (int fm = 0; fm < 2; ++fm) {
        size_t off = (size_t)(m0 + fm * 16 + col16) * lda + ka;
        aHi[fm] = *reinterpret_cast<const short8*>(aHiBase + off);
        aLo[fm] = *reinterpret_cast<const short8*>(aLoBase + off);
    }
    int kb = kglob + 8 * g4;
    #pragma unroll
    for (int fn = 0; fn < 2; ++fn) {
        size_t off = (size_t)(jabs0 + fn * 16 + col16) * KTOT + kb;
        bHi[fn] = *reinterpret_cast<const short8*>(WHi + off);
        bLo[fn] = *reinterpret_cast<const short8*>(WLo + off);
    }
    #pragma unroll
    for (int fm = 0; fm < 2; ++fm)
        #pragma unroll
        for (int fn = 0; fn < 2; ++fn) {
            acc[fm][fn] = __builtin_amdgcn_mfma_f32_16x16x32_bf16(aHi[fm], bHi[fn], acc[fm][fn], 0, 0, 0);
            acc[fm][fn] = __builtin_amdgcn_mfma_f32_16x16x32_bf16(aHi[fm], bLo[fn], acc[fm][fn], 0, 0, 0);
            acc[fm][fn] = __builtin_amdgcn_mfma_f32_16x16x32_bf16(aLo[fm], bHi[fn], acc[fm][fn], 0, 0, 0);
        }
}

__global__ __launch_bounds__(256) void lstm_step_kernel(
    const unsigned short* __restrict__ embHi_t, const unsigned short* __restrict__ embLo_t,
    const unsigned short* __restrict__ hInHi,   const unsigned short* __restrict__ hInLo,
    const unsigned short* __restrict__ WHi,     const unsigned short* __restrict__ WLo,
    const float* __restrict__ b_ih, const float* __restrict__ b_hh,
    float* __restrict__ c,
    unsigned short* __restrict__ hOutHi, unsigned short* __restrict__ hOutLo,
    float* __restrict__ out, int is_last)
{
    int m0 = blockIdx.x * 32;
    int nh0 = blockIdx.y * 32;
    int wave = threadIdx.x >> 6;     // gate index 0..3 (i,f,g,o)
    int lane = threadIdx.x & 63;
    int col16 = lane & 15;
    int g4 = lane >> 4;
    int jabs0 = wave * HID + nh0;

    f32x4 acc[2][2] = {};

    for (int k0 = 0; k0 < EMBD; k0 += 32)
        do_k32(embHi_t, embLo_t, EMBD, k0, WHi, WLo, k0, m0, jabs0, col16, g4, acc);
    for (int k0 = 0; k0 < HID; k0 += 32)
        do_k32(hInHi, hInLo, HID, k0, WHi, WLo, EMBD + k0, m0, jabs0, col16, g4, acc);

    __shared__ float gbuf[4][32][32];
    #pragma unroll
    for (int fm = 0; fm < 2; ++fm)
        #pragma unroll
        for (int fn = 0; fn < 2; ++fn)
            #pragma unroll
            for (int r = 0; r < 4; ++r) {
                int ml = fm * 16 + g4 * 4 + r;
                int nl = fn * 16 + col16;
                gbuf[wave][ml][nl] = acc[fm][fn][r];
            }
    __syncthreads();

    for (int idx = threadIdx.x; idx < 32 * 32; idx += 256) {
        int ml = idx >> 5, nl = idx & 31;
        int b = m0 + ml, jh = nh0 + nl;
        float gi = gbuf[0][ml][nl] + b_ih[jh]           + b_hh[jh];
        float gf = gbuf[1][ml][nl] + b_ih[HID + jh]     + b_hh[HID + jh];
        float gg = gbuf[2][ml][nl] + b_ih[2 * HID + jh] + b_hh[2 * HID + jh];
        float go = gbuf[3][ml][nl] + b_ih[3 * HID + jh] + b_hh[3 * HID + jh];
        float si = 1.0f / (1.0f + expf(-gi));
        float sf = 1.0f / (1.0f + expf(-gf));
        float so = 1.0f / (1.0f + expf(-go));
        float tg = tanhf(gg);
        size_t p = (size_t)b * HID + jh;
        float cNew = sf * c[p] + si * tg;
        float hNew = so * tanhf(cNew);
        c[p] = cNew;
        unsigned short hh, hl;
        split_bf16(hNew, hh, hl);
        hOutHi[p] = hh;
        hOutLo[p] = hl;
        if (is_last) out[p] = hNew;
    }
}

extern "C" void kernel_launch(void* const* d_in, const int* in_sizes, int n_in,
                              void* d_out, int out_size, void* d_ws, size_t ws_size,
                              hipStream_t stream) {
    const int*   qv   = (const int*)d_in[0];
    // d_in[1] = ques_len (unused by the reference recurrence)
    const float* Wemb = (const float*)d_in[2];
    const float* Wih  = (const float*)d_in[3];
    const float* Whh  = (const float*)d_in[4];
    const float* b_ih = (const float*)d_in[5];
    const float* b_hh = (const float*)d_in[6];
    float* out = (float*)d_out;

    char* ws = (char*)d_ws;
    size_t off = 0;
    unsigned short* embHi = (unsigned short*)(ws + off); off += (size_t)SEQW * NBATCH * EMBD * 2;   // 6,815,744
    unsigned short* embLo = (unsigned short*)(ws + off); off += (size_t)SEQW * NBATCH * EMBD * 2;
    unsigned short* WHi   = (unsigned short*)(ws + off); off += (size_t)4 * HID * KTOT * 2;         // 12,582,912
    unsigned short* WLo   = (unsigned short*)(ws + off); off += (size_t)4 * HID * KTOT * 2;
    unsigned short* hHi0  = (unsigned short*)(ws + off); off += (size_t)NBATCH * HID * 2;
    unsigned short* hHi1  = (unsigned short*)(ws + off); off += (size_t)NBATCH * HID * 2;
    unsigned short* hLo0  = (unsigned short*)(ws + off); off += (size_t)NBATCH * HID * 2;
    unsigned short* hLo1  = (unsigned short*)(ws + off); off += (size_t)NBATCH * HID * 2;
    float* c              = (float*)(ws + off);          off += (size_t)NBATCH * HID * 4;

    unsigned short* hHiBuf[2] = { hHi0, hHi1 };
    unsigned short* hLoBuf[2] = { hLo0, hLo1 };

    init_kernel<<<NBATCH, 256, 0, stream>>>(c, hHi0, hLo0);
    embed_kernel<<<SEQW * NBATCH, 64, 0, stream>>>(qv, Wemb, embHi, embLo);
    convw_kernel<<<4 * HID, 256, 0, stream>>>(Wih, Whh, WHi, WLo);

    for (int t = 0; t < SEQW; ++t) {
        int cur = t & 1, nxt = (t + 1) & 1;
        lstm_step_kernel<<<dim3(8, 32), 256, 0, stream>>>(
            embHi + (size_t)t * NBATCH * EMBD, embLo + (size_t)t * NBATCH * EMBD,
            hHiBuf[cur], hLoBuf[cur],
            WHi, WLo, b_ih, b_hh, c,
            hHiBuf[nxt], hLoBuf[nxt],
            out, (t == SEQW - 1) ? 1 : 0);
    }
}